// Round 5
// baseline (237.745 us; speedup 1.0000x reference)
//
#include <hip/hip_runtime.h>

typedef float v2f __attribute__((ext_vector_type(2)));

#define D_DIM 512
#define C_CLS 100
#define SAMP 4     // samples per block
#define NT 256     // threads; 200 active = 8 dq * 25 cq

// X-stage and partials share LDS (xs fully consumed before partials written).
union SMemU {
    float xs[SAMP][544];            // col i stored at i + (i>>6)*4 (bank de-alias)
    struct {
        float4 A[SAMP][8][25];      // l1 partials  [si][dq][cq]
        float4 B[SAMP][8][25];      // dot partials [si][dq][cq]
        float4 G[8][25];            // gsq partials [dq][cq]
    } p;
};

__global__ __launch_bounds__(NT, 5) void cls_kernel(const float* __restrict__ X,
                                                    const float* __restrict__ grp,
                                                    float* __restrict__ out) {
    __shared__ SMemU sm;
    __shared__ float redA[SAMP][25];
    __shared__ float redB[SAMP][25];
    __shared__ float xsqs[SAMP];

    const int t = threadIdx.x;
    const int n0 = blockIdx.x * SAMP;

    // Stage 4 X rows, swizzled: +4-float pad every 64 cols
    {
        const float4* Xv = (const float4*)(X + (size_t)n0 * D_DIM);
        for (int i = t; i < SAMP * D_DIM / 4; i += NT) {
            int row = i >> 7;
            int c4 = i & 127;
            *(float4*)&sm.xs[row][c4 * 4 + (c4 >> 4) * 4] = Xv[i];
        }
    }
    __syncthreads();

    // ||x||^2 per row: 32 threads/row, shuffle-reduce
    if (t < 128) {
        const int r = t >> 5, j = t & 31;
        float v = 0.f;
#pragma unroll
        for (int k = 0; k < 4; ++k) {
            int col = j * 4 + k * 128;
            float4 a = *(const float4*)&sm.xs[r][col + (col >> 6) * 4];
            v += a.x * a.x + a.y * a.y + a.z * a.z + a.w * a.w;
        }
#pragma unroll
        for (int m = 16; m > 0; m >>= 1) v += __shfl_xor(v, m, 32);
        if (j == 0) xsqs[r] = v;
    }

    const bool act = (t < 200);
    const int dq = t / 25;
    const int cq = t - dq * 25;

    float l1[4][4];
    v2f dtl[4], dth[4];
    v2f gsql = {0.f, 0.f}, gsqh = {0.f, 0.f};
#pragma unroll
    for (int i = 0; i < 4; ++i) {
        dtl[i] = (v2f){0.f, 0.f};
        dth[i] = (v2f){0.f, 0.f};
#pragma unroll
        for (int j = 0; j < 4; ++j) l1[i][j] = 0.f;
    }

    if (act) {
        const float* gp = grp + cq * 4;
        const int dbase = dq * 64;
        const int xbase = dbase + dq * 4;     // swizzled xs base (d4>>6 == dq)

        float4 gbuf[4];
#pragma unroll
        for (int k = 0; k < 4; ++k)
            gbuf[k] = *(const float4*)&gp[(dbase + k) * C_CLS];

#pragma unroll
        for (int dd = 0; dd < 64; dd += 4) {
            float4 gg[4];
#pragma unroll
            for (int k = 0; k < 4; ++k) gg[k] = gbuf[k];
            if (dd < 60) {                    // prefetch next 4 d-columns
#pragma unroll
                for (int k = 0; k < 4; ++k)
                    gbuf[k] = *(const float4*)&gp[(dbase + dd + 4 + k) * C_CLS];
            }
            float xr[4][4];   // [si][k]
#pragma unroll
            for (int si = 0; si < 4; ++si)
                *(float4*)&xr[si][0] = *(const float4*)&sm.xs[si][xbase + dd];
#pragma unroll
            for (int k = 0; k < 4; ++k) {
                v2f glo = {gg[k].x, gg[k].y};
                v2f ghi = {gg[k].z, gg[k].w};
                gsql += glo * glo;
                gsqh += ghi * ghi;
#pragma unroll
                for (int si = 0; si < 4; ++si) {
                    float x = xr[si][k];
                    v2f x2 = {x, x};
                    v2f el = x2 - glo;
                    v2f eh = x2 - ghi;
                    l1[si][0] += fabsf(el.x);
                    l1[si][1] += fabsf(el.y);
                    l1[si][2] += fabsf(eh.x);
                    l1[si][3] += fabsf(eh.y);
                    dtl[si] += x2 * glo;
                    dth[si] += x2 * ghi;
                }
            }
        }
    }
    __syncthreads();   // everyone done reading xs before partials overwrite it

    if (act) {
#pragma unroll
        for (int si = 0; si < 4; ++si) {
            sm.p.A[si][dq][cq] = float4{l1[si][0], l1[si][1], l1[si][2], l1[si][3]};
            sm.p.B[si][dq][cq] = float4{dtl[si].x, dtl[si].y, dth[si].x, dth[si].y};
        }
        sm.p.G[dq][cq] = float4{gsql.x, gsql.y, gsqh.x, gsqh.y};
    }
    __syncthreads();

    // Phase 2: thread (s = t/25 in 0..3, c2 = t%25) combines 8 dq partials
    const int s  = t / 25;
    const int c2 = t - s * 25;
    const bool act2 = (t < 100);

    float l1c[4] = {0.f, 0.f, 0.f, 0.f};
    float dtc[4] = {0.f, 0.f, 0.f, 0.f};
    float gsc[4] = {0.f, 0.f, 0.f, 0.f};
    if (act2) {
#pragma unroll
        for (int q = 0; q < 8; ++q) {
            float4 a = sm.p.A[s][q][c2];
            float4 b = sm.p.B[s][q][c2];
            float4 c = sm.p.G[q][c2];
            l1c[0] += a.x; l1c[1] += a.y; l1c[2] += a.z; l1c[3] += a.w;
            dtc[0] += b.x; dtc[1] += b.y; dtc[2] += b.z; dtc[3] += b.w;
            gsc[0] += c.x; gsc[1] += c.y; gsc[2] += c.z; gsc[3] += c.w;
        }
    }

    float cs[4] = {0.f, 0.f, 0.f, 0.f};
    if (act2) {
        float xq = xsqs[s];
#pragma unroll
        for (int c = 0; c < 4; ++c)
            cs[c] = dtc[c] / fmaxf(sqrtf(xq * gsc[c]), 1e-8f);
        redA[s][c2] = fminf(fminf(l1c[0], l1c[1]), fminf(l1c[2], l1c[3]));
        redB[s][c2] = fmaxf(fmaxf(cs[0], cs[1]), fmaxf(cs[2], cs[3]));
    }
    __syncthreads();

    float minl1 = 0.f, maxcs = 0.f;
    if (act2) {
        minl1 = redA[s][0];
        maxcs = redB[s][0];
        for (int k = 1; k < 25; ++k) {
            minl1 = fminf(minl1, redA[s][k]);
            maxcs = fmaxf(maxcs, redB[s][k]);
        }
    }
    __syncthreads();

    if (act2) {
        redA[s][c2] = __expf(minl1 - l1c[0]) + __expf(minl1 - l1c[1]) +
                      __expf(minl1 - l1c[2]) + __expf(minl1 - l1c[3]);
        redB[s][c2] = __expf(cs[0] - maxcs) + __expf(cs[1] - maxcs) +
                      __expf(cs[2] - maxcs) + __expf(cs[3] - maxcs);
    }
    __syncthreads();

    if (act2) {
        float s1 = 0.f, s2 = 0.f;
        for (int k = 0; k < 25; ++k) { s1 += redA[s][k]; s2 += redB[s][k]; }
        float f = maxcs / (s1 * s2);
        float4 o;
        o.x = f * __expf(cs[0] - maxcs) * __expf(minl1 - l1c[0]);
        o.y = f * __expf(cs[1] - maxcs) * __expf(minl1 - l1c[1]);
        o.z = f * __expf(cs[2] - maxcs) * __expf(minl1 - l1c[2]);
        o.w = f * __expf(cs[3] - maxcs) * __expf(minl1 - l1c[3]);
        *(float4*)&out[(size_t)(n0 + s) * C_CLS + c2 * 4] = o;
    }
}

extern "C" void kernel_launch(void* const* d_in, const int* in_sizes, int n_in,
                              void* d_out, int out_size, void* d_ws, size_t ws_size,
                              hipStream_t stream) {
    const float* X   = (const float*)d_in[0];   // [4096, 512] f32
    const float* grp = (const float*)d_in[1];   // [1, 512, 100] f32
    float* out = (float*)d_out;                 // [4096, 100] f32
    (void)d_ws; (void)ws_size;

    cls_kernel<<<4096 / SAMP, NT, 0, stream>>>(X, grp, out);
}

// Round 6
// 180.247 us; speedup vs baseline: 1.3190x; 1.3190x over previous
//
#include <hip/hip_runtime.h>

typedef float v2f __attribute__((ext_vector_type(2)));

#define D_DIM 512
#define C_CLS 100
#define SAMP 4     // samples per block
#define NT 256     // threads; 200 active = 8 dq * 25 cq

// X-stage and partials share LDS (xs fully consumed before partials written).
union SMemU {
    float xs[SAMP][544];            // col i stored at i + (i>>6)*4 (bank de-alias)
    struct {
        float4 A[SAMP][8][25];      // l1 partials  [si][dq][cq]
        float4 B[SAMP][8][25];      // dot partials [si][dq][cq]
        float4 G[8][25];            // gsq partials [dq][cq]
    } p;
};

// NOTE: min-waves/EU = 4 (VGPR cap 128). DO NOT raise to 5: per-SIMD VGPR file
// is 512 regs, so 5 waves caps at ~96 VGPR -> the prefetch+accumulator set
// (~110 live) spills to scratch (R5: 678 MB WRITE_SIZE, 7x slowdown).
__global__ __launch_bounds__(NT, 4) void cls_kernel(const float* __restrict__ X,
                                                    const float* __restrict__ grp,
                                                    float* __restrict__ out) {
    __shared__ SMemU sm;
    __shared__ float redA[SAMP][25];
    __shared__ float redB[SAMP][25];
    __shared__ float xsqs[SAMP];

    const int t = threadIdx.x;
    const int n0 = blockIdx.x * SAMP;

    // Stage 4 X rows, swizzled: +4-float pad every 64 cols
    {
        const float4* Xv = (const float4*)(X + (size_t)n0 * D_DIM);
        for (int i = t; i < SAMP * D_DIM / 4; i += NT) {
            int row = i >> 7;
            int c4 = i & 127;
            *(float4*)&sm.xs[row][c4 * 4 + (c4 >> 4) * 4] = Xv[i];
        }
    }
    __syncthreads();

    // ||x||^2 per row: 32 threads/row, shuffle-reduce
    if (t < 128) {
        const int r = t >> 5, j = t & 31;
        float v = 0.f;
#pragma unroll
        for (int k = 0; k < 4; ++k) {
            int col = j * 4 + k * 128;
            float4 a = *(const float4*)&sm.xs[r][col + (col >> 6) * 4];
            v += a.x * a.x + a.y * a.y + a.z * a.z + a.w * a.w;
        }
#pragma unroll
        for (int m = 16; m > 0; m >>= 1) v += __shfl_xor(v, m, 32);
        if (j == 0) xsqs[r] = v;
    }

    const bool act = (t < 200);
    const int dq = t / 25;
    const int cq = t - dq * 25;

    float l1[4][4];
    v2f dtl[4], dth[4];
    v2f gsql = {0.f, 0.f}, gsqh = {0.f, 0.f};
#pragma unroll
    for (int i = 0; i < 4; ++i) {
        dtl[i] = (v2f){0.f, 0.f};
        dth[i] = (v2f){0.f, 0.f};
#pragma unroll
        for (int j = 0; j < 4; ++j) l1[i][j] = 0.f;
    }

    if (act) {
        const float* gp = grp + cq * 4;
        const int dbase = dq * 64;
        const int xbase = dbase + dq * 4;     // swizzled xs base (d4>>6 == dq)

        float4 gbuf[4];
#pragma unroll
        for (int k = 0; k < 4; ++k)
            gbuf[k] = *(const float4*)&gp[(dbase + k) * C_CLS];

#pragma unroll
        for (int dd = 0; dd < 64; dd += 4) {
            float4 gg[4];
#pragma unroll
            for (int k = 0; k < 4; ++k) gg[k] = gbuf[k];
            if (dd < 60) {                    // prefetch next 4 d-columns
#pragma unroll
                for (int k = 0; k < 4; ++k)
                    gbuf[k] = *(const float4*)&gp[(dbase + dd + 4 + k) * C_CLS];
            }
            float xr[4][4];   // [si][k]
#pragma unroll
            for (int si = 0; si < 4; ++si)
                *(float4*)&xr[si][0] = *(const float4*)&sm.xs[si][xbase + dd];
#pragma unroll
            for (int k = 0; k < 4; ++k) {
                v2f glo = {gg[k].x, gg[k].y};
                v2f ghi = {gg[k].z, gg[k].w};
                gsql += glo * glo;
                gsqh += ghi * ghi;
#pragma unroll
                for (int si = 0; si < 4; ++si) {
                    float x = xr[si][k];
                    v2f x2 = {x, x};
                    v2f el = x2 - glo;
                    v2f eh = x2 - ghi;
                    l1[si][0] += fabsf(el.x);
                    l1[si][1] += fabsf(el.y);
                    l1[si][2] += fabsf(eh.x);
                    l1[si][3] += fabsf(eh.y);
                    dtl[si] += x2 * glo;
                    dth[si] += x2 * ghi;
                }
            }
        }
    }
    __syncthreads();   // everyone done reading xs before partials overwrite it

    if (act) {
#pragma unroll
        for (int si = 0; si < 4; ++si) {
            sm.p.A[si][dq][cq] = float4{l1[si][0], l1[si][1], l1[si][2], l1[si][3]};
            sm.p.B[si][dq][cq] = float4{dtl[si].x, dtl[si].y, dth[si].x, dth[si].y};
        }
        sm.p.G[dq][cq] = float4{gsql.x, gsql.y, gsqh.x, gsqh.y};
    }
    __syncthreads();

    // Phase 2: thread (s = t/25 in 0..3, c2 = t%25) combines 8 dq partials
    const int s  = t / 25;
    const int c2 = t - s * 25;
    const bool act2 = (t < 100);

    float l1c[4] = {0.f, 0.f, 0.f, 0.f};
    float dtc[4] = {0.f, 0.f, 0.f, 0.f};
    float gsc[4] = {0.f, 0.f, 0.f, 0.f};
    if (act2) {
#pragma unroll
        for (int q = 0; q < 8; ++q) {
            float4 a = sm.p.A[s][q][c2];
            float4 b = sm.p.B[s][q][c2];
            float4 c = sm.p.G[q][c2];
            l1c[0] += a.x; l1c[1] += a.y; l1c[2] += a.z; l1c[3] += a.w;
            dtc[0] += b.x; dtc[1] += b.y; dtc[2] += b.z; dtc[3] += b.w;
            gsc[0] += c.x; gsc[1] += c.y; gsc[2] += c.z; gsc[3] += c.w;
        }
    }

    float cs[4] = {0.f, 0.f, 0.f, 0.f};
    if (act2) {
        float xq = xsqs[s];
#pragma unroll
        for (int c = 0; c < 4; ++c)
            cs[c] = dtc[c] / fmaxf(sqrtf(xq * gsc[c]), 1e-8f);
        redA[s][c2] = fminf(fminf(l1c[0], l1c[1]), fminf(l1c[2], l1c[3]));
        redB[s][c2] = fmaxf(fmaxf(cs[0], cs[1]), fmaxf(cs[2], cs[3]));
    }
    __syncthreads();

    float minl1 = 0.f, maxcs = 0.f;
    if (act2) {
        minl1 = redA[s][0];
        maxcs = redB[s][0];
        for (int k = 1; k < 25; ++k) {
            minl1 = fminf(minl1, redA[s][k]);
            maxcs = fmaxf(maxcs, redB[s][k]);
        }
    }
    __syncthreads();

    if (act2) {
        redA[s][c2] = __expf(minl1 - l1c[0]) + __expf(minl1 - l1c[1]) +
                      __expf(minl1 - l1c[2]) + __expf(minl1 - l1c[3]);
        redB[s][c2] = __expf(cs[0] - maxcs) + __expf(cs[1] - maxcs) +
                      __expf(cs[2] - maxcs) + __expf(cs[3] - maxcs);
    }
    __syncthreads();

    if (act2) {
        float s1 = 0.f, s2 = 0.f;
        for (int k = 0; k < 25; ++k) { s1 += redA[s][k]; s2 += redB[s][k]; }
        float f = maxcs / (s1 * s2);
        float4 o;
        o.x = f * __expf(cs[0] - maxcs) * __expf(minl1 - l1c[0]);
        o.y = f * __expf(cs[1] - maxcs) * __expf(minl1 - l1c[1]);
        o.z = f * __expf(cs[2] - maxcs) * __expf(minl1 - l1c[2]);
        o.w = f * __expf(cs[3] - maxcs) * __expf(minl1 - l1c[3]);
        *(float4*)&out[(size_t)(n0 + s) * C_CLS + c2 * 4] = o;
    }
}

extern "C" void kernel_launch(void* const* d_in, const int* in_sizes, int n_in,
                              void* d_out, int out_size, void* d_ws, size_t ws_size,
                              hipStream_t stream) {
    const float* X   = (const float*)d_in[0];   // [4096, 512] f32
    const float* grp = (const float*)d_in[1];   // [1, 512, 100] f32
    float* out = (float*)d_out;                 // [4096, 100] f32
    (void)d_ws; (void)ws_size;

    cls_kernel<<<4096 / SAMP, NT, 0, stream>>>(X, grp, out);
}

// Round 7
// 38.210 us; speedup vs baseline: 6.2220x; 4.7172x over previous
//
#include <hip/hip_runtime.h>

typedef float v2f __attribute__((ext_vector_type(2)));

#define D_DIM 512
#define C_CLS 100
#define SAMP 8
#define NT 256
#define BD 64                  // d-rows per staged chunk
#define NCHUNK (D_DIM / BD)    // 8

// LDS: grp chunk double-buffer (51.2 KB) unioned with end-of-kernel partials.
struct SMem {
    union {
        float4 g[2][BD * 25];          // [buf][row*25 + cq]; row-major, linear (global_load_lds dest)
        struct {
            float4 A[SAMP][4][25];     // l1  partials [samp][dsub][cq]
            float4 B[SAMP][4][25];     // dot partials
            float4 G[4][25];           // gsq partials [dsub][cq]
        } p;
    } u;
    float redA[SAMP][25];
    float redB[SAMP][25];
    float xsqs[SAMP];
};

__device__ static inline void load16_lds(const float* g, void* l) {
    // async global->LDS, 16B/lane; LDS dest = wave-uniform base + lane*16 (linear)
    __builtin_amdgcn_global_load_lds(
        (const __attribute__((address_space(1))) unsigned int*)g,
        (__attribute__((address_space(3))) unsigned int*)l, 16, 0, 0);
}

// wave wv stages 1KB slabs iss = wv, wv+4, ... of the 25.6KB chunk
#define STAGE(buf, c)                                                          \
    for (int iss = wv; iss < 25; iss += 4)                                     \
        load16_lds(grp + (size_t)(c) * (BD * C_CLS) + iss * 256 + lane * 4,    \
                   (void*)&sm.u.g[buf][iss * 64]);

__global__ __launch_bounds__(NT, 4) void cls_kernel(const float* __restrict__ X,
                                                    const float* __restrict__ grp,
                                                    float* __restrict__ out) {
    __shared__ SMem sm;

    const int t = threadIdx.x;
    const int lane = t & 63;
    const int wv = t >> 6;            // wave id = dsub (d-slice of 16 within chunk)
    const int n0 = blockIdx.x * SAMP;

    // kick off chunk 0 staging immediately
    STAGE(0, 0)

    // ||x||^2 per sample row while stage-0 flies: 32 threads/row, shuffle-reduce
    {
        const int r = t >> 5, j = t & 31;
        float v = 0.f;
#pragma unroll
        for (int k = 0; k < 4; ++k) {
            float4 a = *(const float4*)&X[(size_t)(n0 + r) * D_DIM + j * 4 + k * 128];
            v += a.x * a.x + a.y * a.y + a.z * a.z + a.w * a.w;
        }
#pragma unroll
        for (int m = 16; m > 0; m >>= 1) v += __shfl_xor(v, m, 32);
        if (j == 0) sm.xsqs[r] = v;
    }

    const int cq = lane % 25;         // class quad
    const int sg = lane / 25;         // sample group (0,1); lanes >= 50 idle in compute
    const bool cact = (lane < 50);

    float l1[4][4];
    v2f dtl[4], dth[4];
    v2f gsql = {0.f, 0.f}, gsqh = {0.f, 0.f};
#pragma unroll
    for (int i = 0; i < 4; ++i) {
        dtl[i] = (v2f){0.f, 0.f};
        dth[i] = (v2f){0.f, 0.f};
#pragma unroll
        for (int j = 0; j < 4; ++j) l1[i][j] = 0.f;
    }

    asm volatile("s_waitcnt vmcnt(0)" ::: "memory");
    __syncthreads();                  // chunk 0 resident

    const float* xb = X + (size_t)(n0 + sg * 4) * D_DIM;   // 4 sample rows, stride D_DIM

    int cb = 0;
#pragma unroll 1
    for (int c = 0; c < NCHUNK; ++c) {
        if (c + 1 < NCHUNK) { STAGE(cb ^ 1, c + 1) }      // async prefetch next chunk

        if (cact) {
            const float4* gbase = &sm.u.g[cb][wv * 16 * 25 + cq];
            const int dglob = c * BD + wv * 16;
#pragma unroll 2
            for (int dd4 = 0; dd4 < 16; dd4 += 4) {
                float xr[4][4];
#pragma unroll
                for (int si = 0; si < 4; ++si)
                    *(float4*)&xr[si][0] =
                        *(const float4*)&xb[si * D_DIM + dglob + dd4];
#pragma unroll
                for (int k = 0; k < 4; ++k) {
                    float4 g4 = gbase[(dd4 + k) * 25];
                    v2f glo = {g4.x, g4.y};
                    v2f ghi = {g4.z, g4.w};
                    gsql += glo * glo;
                    gsqh += ghi * ghi;
#pragma unroll
                    for (int si = 0; si < 4; ++si) {
                        float x = xr[si][k];
                        v2f x2 = {x, x};
                        v2f el = x2 - glo;
                        v2f eh = x2 - ghi;
                        l1[si][0] += fabsf(el.x);
                        l1[si][1] += fabsf(el.y);
                        l1[si][2] += fabsf(eh.x);
                        l1[si][3] += fabsf(eh.y);
                        dtl[si] += x2 * glo;
                        dth[si] += x2 * ghi;
                    }
                }
            }
        }
        asm volatile("s_waitcnt vmcnt(0)" ::: "memory");
        __syncthreads();              // next chunk landed; this buf free to overwrite
        cb ^= 1;
    }

    // staging buffers dead -> write partials into the union
    if (cact) {
#pragma unroll
        for (int si = 0; si < 4; ++si) {
            sm.u.p.A[sg * 4 + si][wv][cq] =
                float4{l1[si][0], l1[si][1], l1[si][2], l1[si][3]};
            sm.u.p.B[sg * 4 + si][wv][cq] =
                float4{dtl[si].x, dtl[si].y, dth[si].x, dth[si].y};
        }
        if (sg == 0)
            sm.u.p.G[wv][cq] = float4{gsql.x, gsql.y, gsqh.x, gsqh.y};
    }
    __syncthreads();

    // Phase 2: thread (s = t/25 in 0..7, c2 = t%25) combines 4 dsub partials
    const int s  = t / 25;
    const int c2 = t - s * 25;
    const bool act2 = (t < 200);

    float l1c[4] = {0.f, 0.f, 0.f, 0.f};
    float dtc[4] = {0.f, 0.f, 0.f, 0.f};
    float gsc[4] = {0.f, 0.f, 0.f, 0.f};
    if (act2) {
#pragma unroll
        for (int q = 0; q < 4; ++q) {
            float4 a = sm.u.p.A[s][q][c2];
            float4 b = sm.u.p.B[s][q][c2];
            float4 c = sm.u.p.G[q][c2];
            l1c[0] += a.x; l1c[1] += a.y; l1c[2] += a.z; l1c[3] += a.w;
            dtc[0] += b.x; dtc[1] += b.y; dtc[2] += b.z; dtc[3] += b.w;
            gsc[0] += c.x; gsc[1] += c.y; gsc[2] += c.z; gsc[3] += c.w;
        }
    }

    float cs[4] = {0.f, 0.f, 0.f, 0.f};
    if (act2) {
        float xq = sm.xsqs[s];
#pragma unroll
        for (int c = 0; c < 4; ++c)
            cs[c] = dtc[c] / fmaxf(sqrtf(xq * gsc[c]), 1e-8f);
        sm.redA[s][c2] = fminf(fminf(l1c[0], l1c[1]), fminf(l1c[2], l1c[3]));
        sm.redB[s][c2] = fmaxf(fmaxf(cs[0], cs[1]), fmaxf(cs[2], cs[3]));
    }
    __syncthreads();

    float minl1 = 0.f, maxcs = 0.f;
    if (act2) {
        minl1 = sm.redA[s][0];
        maxcs = sm.redB[s][0];
        for (int k = 1; k < 25; ++k) {
            minl1 = fminf(minl1, sm.redA[s][k]);
            maxcs = fmaxf(maxcs, sm.redB[s][k]);
        }
    }
    __syncthreads();

    if (act2) {
        sm.redA[s][c2] = __expf(minl1 - l1c[0]) + __expf(minl1 - l1c[1]) +
                         __expf(minl1 - l1c[2]) + __expf(minl1 - l1c[3]);
        sm.redB[s][c2] = __expf(cs[0] - maxcs) + __expf(cs[1] - maxcs) +
                         __expf(cs[2] - maxcs) + __expf(cs[3] - maxcs);
    }
    __syncthreads();

    if (act2) {
        float s1 = 0.f, s2 = 0.f;
        for (int k = 0; k < 25; ++k) { s1 += sm.redA[s][k]; s2 += sm.redB[s][k]; }
        float f = maxcs / (s1 * s2);
        float4 o;
        o.x = f * __expf(cs[0] - maxcs) * __expf(minl1 - l1c[0]);
        o.y = f * __expf(cs[1] - maxcs) * __expf(minl1 - l1c[1]);
        o.z = f * __expf(cs[2] - maxcs) * __expf(minl1 - l1c[2]);
        o.w = f * __expf(cs[3] - maxcs) * __expf(minl1 - l1c[3]);
        *(float4*)&out[(size_t)(n0 + s) * C_CLS + c2 * 4] = o;
    }
}

extern "C" void kernel_launch(void* const* d_in, const int* in_sizes, int n_in,
                              void* d_out, int out_size, void* d_ws, size_t ws_size,
                              hipStream_t stream) {
    const float* X   = (const float*)d_in[0];   // [4096, 512] f32
    const float* grp = (const float*)d_in[1];   // [1, 512, 100] f32
    float* out = (float*)d_out;                 // [4096, 100] f32
    (void)d_ws; (void)ws_size;

    cls_kernel<<<4096 / SAMP, NT, 0, stream>>>(X, grp, out);
}